// Round 11
// baseline (139.040 us; speedup 1.0000x reference)
//
#include <hip/hip_runtime.h>
#include <hip/hip_bf16.h>

#define EPS 1e-3f
#define NPIX  50176   // 16*56*56
#define NOPIX 12544   // 16*28*28

// ws float offsets
#define OFF_S2   0        // [32][4]  s2
#define OFF_T2   128      // [32][4]  t2
#define OFF_T3   256      // [128]
#define OFF_BSUM 384      // [256]
#define OFF_W3H  640      // f16 [128 k][9 tap][4 ci] pre-scaled by s3 (4608 f16 = 2304 fl)
#define OFF_TPH  2944     // f16 [32 g][4 kk][4 lq][8] t' (4096 f16 = 2048 fl)
#define OFF_WAF  4992     // A-frag f16 W1: [32 g][4 kk][64 lane][8] (32768 f16 = 16384 fl)
#define OFF_WB2  21376    // A-frag f16 W2: [16 ct][4 kk][64 lane][8] (32768 f16 = 16384 fl)
#define OFF_U    37760    // [32 g][50176 px] f16x4 (8B), g-planar

typedef __attribute__((ext_vector_type(4))) float f32x4;
typedef __attribute__((ext_vector_type(8))) _Float16 f16x8;
typedef __attribute__((ext_vector_type(4))) _Float16 f16x4;
typedef __attribute__((ext_vector_type(2))) _Float16 f16x2;

__device__ __forceinline__ unsigned short f2h(float f) {
    union { _Float16 h; unsigned short u; } c;
    c.h = (_Float16)f;                 // RNE
    return c.u;
}

__global__ __launch_bounds__(256)
void prep_kernel(const float* __restrict__ g1, const float* __restrict__ be1,
                 const float* __restrict__ m1, const float* __restrict__ v1,
                 const float* __restrict__ W1, const float* __restrict__ b1,
                 const float* __restrict__ g2, const float* __restrict__ be2,
                 const float* __restrict__ m2, const float* __restrict__ v2,
                 const float* __restrict__ W3, const float* __restrict__ b3,
                 const float* __restrict__ g3, const float* __restrict__ be3,
                 const float* __restrict__ m3, const float* __restrict__ v3,
                 const float* __restrict__ W2, const float* __restrict__ b2,
                 float* __restrict__ ws) {
    int gid = blockIdx.x * 256 + threadIdx.x;
    int stride = gridDim.x * 256;
    // t' f16 table: [g][kk][lq][j]  c = kk*32 + lq*8 + j ; t' = be1/s1 - m1
    {
        unsigned short* tph = (unsigned short*)(ws + OFF_TPH);
        for (int i = gid; i < 4096; i += stride) {
            int j  = i & 7, lq = (i >> 3) & 3, kk = (i >> 5) & 3, g = i >> 7;
            int c = kk*32 + lq*8 + j;
            float s = g1[g*128 + c] * rsqrtf(v1[g*128 + c] + EPS);
            tph[i] = f2h(be1[g*128 + c] / s - m1[g*128 + c]);
        }
    }
    // W1' A-frag table (f16): lane l holds A[m=l&15][k=(l>>4)*8+j], m=f (<4)
    {
        unsigned short* wsu = (unsigned short*)(ws + OFF_WAF);
        for (int i = gid; i < 32768; i += stride) {
            int j    = i & 7;
            int lane = (i >> 3) & 63;
            int kk   = (i >> 9) & 3;
            int g    = i >> 11;
            int f    = lane & 15;
            int c    = kk*32 + (lane >> 4)*8 + j;
            unsigned short v = 0;
            if (f < 4) {
                float s = g1[g*128 + c] * rsqrtf(v1[g*128 + c] + EPS);
                v = f2h(s * W1[g*512 + c*4 + f]);
            }
            wsu[i] = v;
        }
    }
    // W2 A-frag table (f16): [ct][kk][lane][j]; m=co=ct*16+(l&15), k=c=kk*32+(l>>4)*8+j
    {
        unsigned short* wb = (unsigned short*)(ws + OFF_WB2);
        for (int i = gid; i < 32768; i += stride) {
            int j    = i & 7;
            int lane = (i >> 3) & 63;
            int kk   = (i >> 9) & 3;
            int ct   = i >> 11;          // 0..15
            int co = ct*16 + (lane & 15);
            int c  = kk*32 + (lane >> 4)*8 + j;
            wb[i] = f2h(W2[c*256 + co]);
        }
    }
    // W3 f16 [k][tap][ci], pre-scaled by s3  (k = g*4+f)
    {
        unsigned short* w3h = (unsigned short*)(ws + OFF_W3H);
        for (int i = gid; i < 4608; i += stride) {
            int k = i / 36, j = i - k*36;
            int tap = j >> 2, ci = j & 3;
            int g = k >> 2, f = k & 3;
            float s3 = g3[k] * rsqrtf(v3[k] + EPS);
            w3h[i] = f2h(W3[g*144 + tap*16 + ci*4 + f] * s3);
        }
    }
    if (gid < 128) {
        float s2 = g2[gid] * rsqrtf(v2[gid] + EPS);
        ws[OFF_S2 + gid] = s2;
        ws[OFF_T2 + gid] = be2[gid] + (b1[gid] - m2[gid]) * s2;
        float s3 = g3[gid] * rsqrtf(v3[gid] + EPS);
        ws[OFF_T3 + gid] = be3[gid] + (b3[gid] - m3[gid]) * s3;
    } else if (gid >= 256 && gid < 512) {
        int co = gid - 256;
        float acc = 0.f;
        for (int g = 0; g < 32; ++g) acc += b2[g*256 + co];
        ws[OFF_BSUM + co] = acc;
    }
}

// Stage 1 (fp16 MFMA): grid = 392 128-px tilepairs x 2 g-halves; block 512 =
// 8 waves; wave = 2 groups x 128 px (8 t-iters). Tables (af/tph) loaded once
// per wave amortize over 2x px vs R10; one staging barrier per 128 px.
__global__ __launch_bounds__(512, 4)
void stage1_kernel(const float* __restrict__ x,
                   const float* __restrict__ tabs,   // ws
                   float* __restrict__ uout) {       // ws + OFF_U
    __shared__ uint4 xs[2048];     // 32 KB: [128 px][16 chunk ^ (px&15)], chunk = 8 f16
    int tid = threadIdx.x;
    int tp    = blockIdx.x >> 1;   // 128-px tilepair
    int ghalf = blockIdx.x & 1;

    // stage x -> f16 LDS (coalesced reads; paired ds_write_b64, 2-way free)
    {
        const float4* xg = (const float4*)x + (size_t)tp * 4096;
        #pragma unroll
        for (int r = 0; r < 8; ++r) {
            int i = tid + 512*r;
            int px = i >> 5, c4 = i & 31;
            float4 v = xg[i];
            union { f16x4 h; uint2 u; } hv;
            hv.h = (f16x4){(_Float16)v.x, (_Float16)v.y, (_Float16)v.z, (_Float16)v.w};
            int cc = c4 >> 1, hf = c4 & 1;
            ((uint2*)xs)[(px*16 + (cc ^ (px & 15)))*2 + hf] = hv.u;
        }
    }

    int lane = tid & 63;
    int wid  = tid >> 6;
    int g0   = __builtin_amdgcn_readfirstlane(ghalf*16 + wid*2);
    int l15  = lane & 15;
    int lq   = lane >> 4;

    union U4H { uint4 u; f16x8 h; };
    U4H af[2][4];
    {
        const uint4* wafp = (const uint4*)(tabs + OFF_WAF);
        #pragma unroll
        for (int gi = 0; gi < 2; ++gi)
            #pragma unroll
            for (int kk = 0; kk < 4; ++kk)
                af[gi][kk].u = wafp[((g0 + gi)*4 + kk)*64 + lane];
    }
    U4H tph[2][4];
    {
        const uint4* tphp = (const uint4*)(tabs + OFF_TPH);
        #pragma unroll
        for (int gi = 0; gi < 2; ++gi)
            #pragma unroll
            for (int kk = 0; kk < 4; ++kk)
                tph[gi][kk].u = tphp[((g0 + gi)*4 + kk)*4 + lq];
    }
    __syncthreads();

    uint2* Uo = (uint2*)uout;
    const f32x4 zro = {0.f, 0.f, 0.f, 0.f};
    const f16x8 zh = {0, 0, 0, 0, 0, 0, 0, 0};

    #pragma unroll 1
    for (int t = 0; t < 8; ++t) {
        int pxl = t*16 + l15;
        U4H xf[4];
        #pragma unroll
        for (int kk = 0; kk < 4; ++kk)
            xf[kk].u = xs[pxl*16 + ((kk*4 + lq) ^ (pxl & 15))];
        #pragma unroll
        for (int gi = 0; gi < 2; ++gi) {
            int g = g0 + gi;
            f32x4 acc = zro;
            #pragma unroll
            for (int kk = 0; kk < 4; ++kk) {
                f16x8 z = __builtin_elementwise_max(xf[kk].h + tph[gi][kk].h, zh);
                acc = __builtin_amdgcn_mfma_f32_16x16x32_f16(af[gi][kk].h, z, acc, 0, 0, 0);
            }
            const float4 s2v = ((const float4*)(tabs + OFF_S2))[g];
            const float4 t2v = ((const float4*)(tabs + OFF_T2))[g];
            float o0 = fmaxf(fmaf(acc[0], s2v.x, t2v.x), 0.f);
            float o1 = fmaxf(fmaf(acc[1], s2v.y, t2v.y), 0.f);
            float o2 = fmaxf(fmaf(acc[2], s2v.z, t2v.z), 0.f);
            float o3 = fmaxf(fmaf(acc[3], s2v.w, t2v.w), 0.f);
            union { f16x4 h; uint2 u; } val;
            val.h = (f16x4){(_Float16)o0, (_Float16)o1, (_Float16)o2, (_Float16)o3};
            if (lane < 16)
                Uo[(size_t)g * NPIX + tp*128 + t*16 + lane] = val.u;
        }
    }
}

// Stage 2 (fused, quarter-row): block = 7 opx, 256 thr, grid 1792.
// Patch 12.3 KB + vsb 4 KB -> ~16.5 KB LDS -> 7 resident blocks/CU (grid-
// limited), 2x the latency hiding of the half-row version. Conv f16-packed;
// phase B = MFMA D[co16][px16] with px cols 7..15 garbage (unstored).
__global__ __launch_bounds__(256)
void stage2_kernel(const float* __restrict__ x,
                   const float* __restrict__ tabs,   // ws
                   const float* __restrict__ U,      // ws + OFF_U (f16)
                   float* __restrict__ out) {
    __shared__ ushort4 patch[3*16*32];   // [r][c][g ^ c]   12288 B
    __shared__ uint4 vsb[256];           // [16 px][16 chunk ^ px] of 8 f16  4096 B
    __shared__ float res_s[16];

    int tid = threadIdx.x;
    int row = blockIdx.x >> 2;           // b*28 + oh
    int q   = blockIdx.x & 3;            // quarter: opx base = q*7
    int b = row / 28, oh = row - b*28;

    // ---- stage U patch: rows ih = 2oh-1..2oh+1, cols ic = 14q-1 .. 14q+13 ----
    {
        const ushort4* Uu = (const ushort4*)U;
        #pragma unroll 1
        for (int i = tid; i < 1440; i += 256) {
            int g = i / 45;
            int rem = i - g*45;
            int r = rem / 15;            // 0..2
            int c = rem - r*15;          // 0..14
            int ih = 2*oh - 1 + r;
            int ic = 14*q - 1 + c;
            ushort4 v = make_ushort4(0, 0, 0, 0);
            if (ih >= 0 && ic >= 0)
                v = Uu[(size_t)g * NPIX + (b*56 + ih)*56 + ic];
            patch[(r*16 + c)*32 + (g ^ c)] = v;
        }
    }

    // ---- residual: res[p] = sum_c x[b, 2oh, 2(q*7+p), c] ----
    {
        int p = tid >> 5, l = tid & 31;
        if (p < 7) {
            int ow = q*7 + p;
            const float* xp = x + (size_t)((b*56 + 2*oh)*56 + 2*ow) * 128;
            float rv = xp[l] + xp[l+32] + xp[l+64] + xp[l+96];
            #pragma unroll
            for (int off = 16; off; off >>= 1) rv += __shfl_down(rv, off, 32);
            if (l == 0) res_s[p] = rv;
        }
    }

    // conv weights: 9 x f16x4 (uint2) per thread, L2-hot
    int k = tid & 127, s = tid >> 7;     // s in {0,1}
    int g = k >> 2;
    uint2 wk[9];
    {
        const uint2* wk2 = (const uint2*)((const unsigned short*)(tabs + OFF_W3H) + (size_t)k*36);
        #pragma unroll
        for (int tap = 0; tap < 9; ++tap) wk[tap] = wk2[tap];
    }
    float t3 = tabs[OFF_T3 + k];
    __syncthreads();

    // ---- conv (f16 packed): opx = s + 2j; per tap: ds_read_b64 + 2 pk_fma ----
    #pragma unroll
    for (int j = 0; j < 4; ++j) {
        int opx_l = s + 2*j;
        if (opx_l > 6) break;
        f16x2 acc0 = {0, 0}, acc1 = {0, 0};
        #pragma unroll
        for (int kh = 0; kh < 3; ++kh) {
            #pragma unroll
            for (int kw = 0; kw < 3; ++kw) {
                int cc = 2*opx_l + kw;   // 0..14
                union { ushort4 su; f16x4 h; } u;
                u.su = patch[(kh*16 + cc)*32 + (g ^ cc)];
                union { uint2 u2; f16x4 h; } wv;
                wv.u2 = wk[kh*3 + kw];
                f16x2 ulo = __builtin_shufflevector(u.h, u.h, 0, 1);
                f16x2 uhi = __builtin_shufflevector(u.h, u.h, 2, 3);
                f16x2 wlo = __builtin_shufflevector(wv.h, wv.h, 0, 1);
                f16x2 whi = __builtin_shufflevector(wv.h, wv.h, 2, 3);
                acc0 = acc0 + ulo * wlo;   // v_pk_fma_f16 (ffp-contract)
                acc1 = acc1 + uhi * whi;
            }
        }
        float a = ((float)acc0[0] + (float)acc0[1]) + ((float)acc1[0] + (float)acc1[1]);
        float v = fmaxf(a + t3, 0.f);
        ((unsigned short*)vsb)[(opx_l*16 + ((k >> 3) ^ opx_l))*8 + (k & 7)] = f2h(v);
    }
    __syncthreads();

    // ---- phase B: out[px][co] = V @ W2 via MFMA; D[m=co16][n=px16] ----
    {
        int lane = tid & 63;
        int wid  = tid >> 6;             // 0..3, owns co-tiles wid*4..wid*4+3
        int l15  = lane & 15;            // px (valid < 7)
        int lq   = lane >> 4;
        union U4H { uint4 u; f16x8 h; };
        U4H bf[4];
        #pragma unroll
        for (int kk = 0; kk < 4; ++kk)
            bf[kk].u = vsb[l15*16 + ((kk*4 + lq) ^ l15)];
        const uint4* wb2p = (const uint4*)(tabs + OFF_WB2);
        size_t obase = ((size_t)row * 28 + q*7) * 256;
        float rv = res_s[l15];
        #pragma unroll
        for (int c4 = 0; c4 < 4; ++c4) {
            int ct = wid*4 + c4;
            U4H af2[4];
            #pragma unroll
            for (int kk = 0; kk < 4; ++kk)
                af2[kk].u = wb2p[(ct*4 + kk)*64 + lane];
            f32x4 acc = {0.f, 0.f, 0.f, 0.f};
            #pragma unroll
            for (int kk = 0; kk < 4; ++kk)
                acc = __builtin_amdgcn_mfma_f32_16x16x32_f16(af2[kk].h, bf[kk].h, acc, 0, 0, 0);
            float4 bs = *(const float4*)(tabs + OFF_BSUM + ct*16 + lq*4);
            if (l15 < 7) {
                float4 o;
                o.x = acc[0] + bs.x + rv;
                o.y = acc[1] + bs.y + rv;
                o.z = acc[2] + bs.z + rv;
                o.w = acc[3] + bs.w + rv;
                *(float4*)&out[obase + (size_t)l15*256 + ct*16 + lq*4] = o;
            }
        }
    }
}

extern "C" void kernel_launch(void* const* d_in, const int* in_sizes, int n_in,
                              void* d_out, int out_size, void* d_ws, size_t ws_size,
                              hipStream_t stream) {
    const float* x   = (const float*)d_in[0];
    const float* g1  = (const float*)d_in[1];
    const float* be1 = (const float*)d_in[2];
    const float* m1  = (const float*)d_in[3];
    const float* v1  = (const float*)d_in[4];
    const float* W1  = (const float*)d_in[5];
    const float* b1  = (const float*)d_in[6];
    const float* g2  = (const float*)d_in[7];
    const float* be2 = (const float*)d_in[8];
    const float* m2  = (const float*)d_in[9];
    const float* v2  = (const float*)d_in[10];
    const float* W3  = (const float*)d_in[11];
    const float* b3  = (const float*)d_in[12];
    const float* g3  = (const float*)d_in[13];
    const float* be3 = (const float*)d_in[14];
    const float* m3  = (const float*)d_in[15];
    const float* v3  = (const float*)d_in[16];
    const float* W2  = (const float*)d_in[17];
    const float* b2  = (const float*)d_in[18];
    float* out = (float*)d_out;
    float* ws  = (float*)d_ws;

    prep_kernel<<<64, 256, 0, stream>>>(g1, be1, m1, v1, W1, b1, g2, be2, m2,
                                        v2, W3, b3, g3, be3, m3, v3, W2, b2, ws);
    stage1_kernel<<<(NPIX / 128) * 2, 512, 0, stream>>>(x, ws, ws + OFF_U);
    stage2_kernel<<<448 * 4, 256, 0, stream>>>(x, ws, ws + OFF_U, out);
}

// Round 12
// 138.915 us; speedup vs baseline: 1.0009x; 1.0009x over previous
//
#include <hip/hip_runtime.h>
#include <hip/hip_bf16.h>

#define EPS 1e-3f
#define NPIX  50176   // 16*56*56
#define NOPIX 12544   // 16*28*28

// ws float offsets
#define OFF_S2   0        // [32][4]  s2
#define OFF_T2   128      // [32][4]  t2
#define OFF_T3   256      // [128]
#define OFF_BSUM 384      // [256]
#define OFF_W3H  640      // f16 [128 k][9 tap][4 ci] pre-scaled by s3 (4608 f16 = 2304 fl)
#define OFF_TPH  2944     // f16 [32 g][4 kk][4 lq][8] t' (4096 f16 = 2048 fl)
#define OFF_WAF  4992     // A-frag f16 W1: [32 g][4 kk][64 lane][8] (32768 f16 = 16384 fl)
#define OFF_WB2  21376    // A-frag f16 W2: [16 ct][4 kk][64 lane][8] (32768 f16 = 16384 fl)
#define OFF_U    37760    // [32 g][50176 px] f16x4 (8B), g-planar

typedef __attribute__((ext_vector_type(4))) float f32x4;
typedef __attribute__((ext_vector_type(8))) _Float16 f16x8;
typedef __attribute__((ext_vector_type(4))) _Float16 f16x4;
typedef __attribute__((ext_vector_type(2))) _Float16 f16x2;

__device__ __forceinline__ unsigned short f2h(float f) {
    union { _Float16 h; unsigned short u; } c;
    c.h = (_Float16)f;                 // RNE
    return c.u;
}

__global__ __launch_bounds__(256)
void prep_kernel(const float* __restrict__ g1, const float* __restrict__ be1,
                 const float* __restrict__ m1, const float* __restrict__ v1,
                 const float* __restrict__ W1, const float* __restrict__ b1,
                 const float* __restrict__ g2, const float* __restrict__ be2,
                 const float* __restrict__ m2, const float* __restrict__ v2,
                 const float* __restrict__ W3, const float* __restrict__ b3,
                 const float* __restrict__ g3, const float* __restrict__ be3,
                 const float* __restrict__ m3, const float* __restrict__ v3,
                 const float* __restrict__ W2, const float* __restrict__ b2,
                 float* __restrict__ ws) {
    int gid = blockIdx.x * 256 + threadIdx.x;
    int stride = gridDim.x * 256;
    // t' f16 table: [g][kk][lq][j]  c = kk*32 + lq*8 + j ; t' = be1/s1 - m1
    {
        unsigned short* tph = (unsigned short*)(ws + OFF_TPH);
        for (int i = gid; i < 4096; i += stride) {
            int j  = i & 7, lq = (i >> 3) & 3, kk = (i >> 5) & 3, g = i >> 7;
            int c = kk*32 + lq*8 + j;
            float s = g1[g*128 + c] * rsqrtf(v1[g*128 + c] + EPS);
            tph[i] = f2h(be1[g*128 + c] / s - m1[g*128 + c]);
        }
    }
    // W1' A-frag table (f16): lane l holds A[m=l&15][k=(l>>4)*8+j], m=f (<4)
    {
        unsigned short* wsu = (unsigned short*)(ws + OFF_WAF);
        for (int i = gid; i < 32768; i += stride) {
            int j    = i & 7;
            int lane = (i >> 3) & 63;
            int kk   = (i >> 9) & 3;
            int g    = i >> 11;
            int f    = lane & 15;
            int c    = kk*32 + (lane >> 4)*8 + j;
            unsigned short v = 0;
            if (f < 4) {
                float s = g1[g*128 + c] * rsqrtf(v1[g*128 + c] + EPS);
                v = f2h(s * W1[g*512 + c*4 + f]);
            }
            wsu[i] = v;
        }
    }
    // W2 A-frag table (f16): [ct][kk][lane][j]; m=co=ct*16+(l&15), k=c=kk*32+(l>>4)*8+j
    {
        unsigned short* wb = (unsigned short*)(ws + OFF_WB2);
        for (int i = gid; i < 32768; i += stride) {
            int j    = i & 7;
            int lane = (i >> 3) & 63;
            int kk   = (i >> 9) & 3;
            int ct   = i >> 11;          // 0..15
            int co = ct*16 + (lane & 15);
            int c  = kk*32 + (lane >> 4)*8 + j;
            wb[i] = f2h(W2[c*256 + co]);
        }
    }
    // W3 f16 [k][tap][ci], pre-scaled by s3  (k = g*4+f)
    {
        unsigned short* w3h = (unsigned short*)(ws + OFF_W3H);
        for (int i = gid; i < 4608; i += stride) {
            int k = i / 36, j = i - k*36;
            int tap = j >> 2, ci = j & 3;
            int g = k >> 2, f = k & 3;
            float s3 = g3[k] * rsqrtf(v3[k] + EPS);
            w3h[i] = f2h(W3[g*144 + tap*16 + ci*4 + f] * s3);
        }
    }
    if (gid < 128) {
        float s2 = g2[gid] * rsqrtf(v2[gid] + EPS);
        ws[OFF_S2 + gid] = s2;
        ws[OFF_T2 + gid] = be2[gid] + (b1[gid] - m2[gid]) * s2;
        float s3 = g3[gid] * rsqrtf(v3[gid] + EPS);
        ws[OFF_T3 + gid] = be3[gid] + (b3[gid] - m3[gid]) * s3;
    } else if (gid >= 256 && gid < 512) {
        int co = gid - 256;
        float acc = 0.f;
        for (int g = 0; g < 32; ++g) acc += b2[g*256 + co];
        ws[OFF_BSUM + co] = acc;
    }
}

// Stage 1 (fp16 MFMA): grid = 784 tiles x 2 g-halves; block 512 = 8 waves;
// wave = 2 groups x 64 px. ghalf = bid/784 so the two blocks sharing an
// x-tile are 784 apart (784 % 8 == 0 -> same XCD) -> second x read is L2-hit.
__global__ __launch_bounds__(512, 4)
void stage1_kernel(const float* __restrict__ x,
                   const float* __restrict__ tabs,   // ws
                   float* __restrict__ uout) {       // ws + OFF_U
    __shared__ uint4 xs[1024];     // 16 KB: [64 px][16 chunk ^ (px&15)], chunk = 8 f16
    int tid = threadIdx.x;
    int tile  = blockIdx.x & 783;  // == % 784 (784 = 16*49; mask invalid) 
    int ghalf = blockIdx.x >= 784;

    {
        const float4* xg = (const float4*)x + (size_t)tile * 2048;
        #pragma unroll
        for (int r = 0; r < 4; ++r) {
            int i = tid + 512*r;
            int px = i >> 5, c4 = i & 31;
            float4 v = xg[i];
            union { f16x4 h; uint2 u; } hv;
            hv.h = (f16x4){(_Float16)v.x, (_Float16)v.y, (_Float16)v.z, (_Float16)v.w};
            int cc = c4 >> 1, hf = c4 & 1;
            ((uint2*)xs)[(px*16 + (cc ^ (px & 15)))*2 + hf] = hv.u;
        }
    }

    int lane = tid & 63;
    int wid  = tid >> 6;
    int g0   = __builtin_amdgcn_readfirstlane(ghalf*16 + wid*2);
    int l15  = lane & 15;
    int lq   = lane >> 4;

    union U4H { uint4 u; f16x8 h; };
    U4H af[2][4];
    {
        const uint4* wafp = (const uint4*)(tabs + OFF_WAF);
        #pragma unroll
        for (int gi = 0; gi < 2; ++gi)
            #pragma unroll
            for (int kk = 0; kk < 4; ++kk)
                af[gi][kk].u = wafp[((g0 + gi)*4 + kk)*64 + lane];
    }
    U4H tph[2][4];
    {
        const uint4* tphp = (const uint4*)(tabs + OFF_TPH);
        #pragma unroll
        for (int gi = 0; gi < 2; ++gi)
            #pragma unroll
            for (int kk = 0; kk < 4; ++kk)
                tph[gi][kk].u = tphp[((g0 + gi)*4 + kk)*4 + lq];
    }
    __syncthreads();

    uint2* Uo = (uint2*)uout;
    const f32x4 zro = {0.f, 0.f, 0.f, 0.f};
    const f16x8 zh = {0, 0, 0, 0, 0, 0, 0, 0};

    #pragma unroll 1
    for (int t = 0; t < 4; ++t) {
        int pxl = t*16 + l15;
        U4H xf[4];
        #pragma unroll
        for (int kk = 0; kk < 4; ++kk)
            xf[kk].u = xs[pxl*16 + ((kk*4 + lq) ^ (pxl & 15))];
        #pragma unroll
        for (int gi = 0; gi < 2; ++gi) {
            int g = g0 + gi;
            f32x4 acc = zro;
            #pragma unroll
            for (int kk = 0; kk < 4; ++kk) {
                f16x8 z = __builtin_elementwise_max(xf[kk].h + tph[gi][kk].h, zh);
                acc = __builtin_amdgcn_mfma_f32_16x16x32_f16(af[gi][kk].h, z, acc, 0, 0, 0);
            }
            const float4 s2v = ((const float4*)(tabs + OFF_S2))[g];
            const float4 t2v = ((const float4*)(tabs + OFF_T2))[g];
            float o0 = fmaxf(fmaf(acc[0], s2v.x, t2v.x), 0.f);
            float o1 = fmaxf(fmaf(acc[1], s2v.y, t2v.y), 0.f);
            float o2 = fmaxf(fmaf(acc[2], s2v.z, t2v.z), 0.f);
            float o3 = fmaxf(fmaf(acc[3], s2v.w, t2v.w), 0.f);
            union { f16x4 h; uint2 u; } val;
            val.h = (f16x4){(_Float16)o0, (_Float16)o1, (_Float16)o2, (_Float16)o3};
            if (lane < 16)
                Uo[(size_t)g * NPIX + tile*64 + t*16 + lane] = val.u;
        }
    }
}

// Stage 2 (fused, f16 conv + MFMA GEMM): block = half-row (14 opx), 256 thr,
// grid 896. Conv: per tap 1 ds_read_b64 + 2 v_pk_fma_f16 (split accumulators).
// V -> 4KB swizzled f16 LDS; phase B: D[co16][px16] MFMA tiles, A = W2-f16
// table (L2-hot), B = V frags (conflict-free b128). ~27 KB LDS -> 5 blk/CU.
__global__ __launch_bounds__(256)
void stage2_kernel(const float* __restrict__ x,
                   const float* __restrict__ tabs,   // ws
                   const float* __restrict__ U,      // ws + OFF_U (f16)
                   float* __restrict__ out) {
    __shared__ ushort4 patch[3*30*32];   // [r][c][g ^ c]   23040 B
    __shared__ uint4 vsb[256];           // [16 px][16 chunk ^ px] of 8 f16  4096 B
    __shared__ float res_s[16];

    int tid = threadIdx.x;
    int row = blockIdx.x >> 1;           // b*28 + oh
    int qh  = blockIdx.x & 1;            // half: opx base = qh*14
    int b = row / 28, oh = row - b*28;

    // ---- stage U patch: rows ih = 2oh-1..2oh+1, cols ic = 28qh-1 .. 28qh+28 ----
    {
        const ushort4* Uu = (const ushort4*)U;
        #pragma unroll 1
        for (int i = tid; i < 2880; i += 256) {
            int g = i / 90;
            int rem = i - g*90;
            int r = rem / 30;            // 0..2
            int c = rem - r*30;          // 0..29
            int ih = 2*oh - 1 + r;
            int ic = 28*qh - 1 + c;
            ushort4 v = make_ushort4(0, 0, 0, 0);
            if (ih >= 0 && ic >= 0 && ic < 56)
                v = Uu[(size_t)g * NPIX + (b*56 + ih)*56 + ic];
            patch[(r*30 + c)*32 + (g ^ c)] = v;
        }
    }

    // ---- residual: res[p] = sum_c x[b, 2oh, 2(qh*14+p), c] ----
    {
        int p = tid >> 4, l = tid & 15;
        if (p < 14) {
            int ow = qh*14 + p;
            const float* xp = x + (size_t)((b*56 + 2*oh)*56 + 2*ow) * 128 + l;
            float rv = 0.f;
            #pragma unroll
            for (int c = 0; c < 8; ++c) rv += xp[c*16];
            #pragma unroll
            for (int off = 8; off; off >>= 1) rv += __shfl_down(rv, off, 16);
            if (l == 0) res_s[p] = rv;
        }
    }

    // conv weights: 9 x f16x4 (uint2) per thread, L2-hot
    int k = tid & 127, s = tid >> 7;     // s in {0,1}
    int g = k >> 2;
    uint2 wk[9];
    {
        const uint2* wk2 = (const uint2*)((const unsigned short*)(tabs + OFF_W3H) + (size_t)k*36);
        #pragma unroll
        for (int tap = 0; tap < 9; ++tap) wk[tap] = wk2[tap];
    }
    float t3 = tabs[OFF_T3 + k];
    __syncthreads();

    // ---- conv (f16 packed): opx = s + 2j; per tap: ds_read_b64 + 2 pk_fma ----
    #pragma unroll 1
    for (int j = 0; j < 7; ++j) {
        int opx_l = s + 2*j;
        f16x2 acc0 = {0, 0}, acc1 = {0, 0};
        #pragma unroll
        for (int kh = 0; kh < 3; ++kh) {
            #pragma unroll
            for (int kw = 0; kw < 3; ++kw) {
                int cc = 2*opx_l + kw;   // 0..28
                union { ushort4 su; f16x4 h; } u;
                u.su = patch[(kh*30 + cc)*32 + (g ^ cc)];
                union { uint2 u2; f16x4 h; } wv;
                wv.u2 = wk[kh*3 + kw];
                f16x2 ulo = __builtin_shufflevector(u.h, u.h, 0, 1);
                f16x2 uhi = __builtin_shufflevector(u.h, u.h, 2, 3);
                f16x2 wlo = __builtin_shufflevector(wv.h, wv.h, 0, 1);
                f16x2 whi = __builtin_shufflevector(wv.h, wv.h, 2, 3);
                acc0 = acc0 + ulo * wlo;   // v_pk_fma_f16 (ffp-contract)
                acc1 = acc1 + uhi * whi;
            }
        }
        float a = ((float)acc0[0] + (float)acc0[1]) + ((float)acc1[0] + (float)acc1[1]);
        float v = fmaxf(a + t3, 0.f);
        ((unsigned short*)vsb)[(opx_l*16 + ((k >> 3) ^ opx_l))*8 + (k & 7)] = f2h(v);
    }
    __syncthreads();

    // ---- phase B: out[px][co] = V @ W2 via MFMA; D[m=co16][n=px16] ----
    {
        int lane = tid & 63;
        int wid  = tid >> 6;             // 0..3, owns co-tiles wid*4..wid*4+3
        int l15  = lane & 15;            // px
        int lq   = lane >> 4;
        union U4H { uint4 u; f16x8 h; };
        U4H bf[4];
        #pragma unroll
        for (int kk = 0; kk < 4; ++kk)
            bf[kk].u = vsb[l15*16 + ((kk*4 + lq) ^ l15)];
        const uint4* wb2p = (const uint4*)(tabs + OFF_WB2);
        size_t obase = ((size_t)row * 28 + qh*14) * 256;
        float rv = res_s[l15];
        #pragma unroll
        for (int c4 = 0; c4 < 4; ++c4) {
            int ct = wid*4 + c4;
            U4H af2[4];
            #pragma unroll
            for (int kk = 0; kk < 4; ++kk)
                af2[kk].u = wb2p[(ct*4 + kk)*64 + lane];
            f32x4 acc = {0.f, 0.f, 0.f, 0.f};
            #pragma unroll
            for (int kk = 0; kk < 4; ++kk)
                acc = __builtin_amdgcn_mfma_f32_16x16x32_f16(af2[kk].h, bf[kk].h, acc, 0, 0, 0);
            float4 bs = *(const float4*)(tabs + OFF_BSUM + ct*16 + lq*4);
            if (l15 < 14) {
                float4 o;
                o.x = acc[0] + bs.x + rv;
                o.y = acc[1] + bs.y + rv;
                o.z = acc[2] + bs.z + rv;
                o.w = acc[3] + bs.w + rv;
                *(float4*)&out[obase + (size_t)l15*256 + ct*16 + lq*4] = o;
            }
        }
    }
}

extern "C" void kernel_launch(void* const* d_in, const int* in_sizes, int n_in,
                              void* d_out, int out_size, void* d_ws, size_t ws_size,
                              hipStream_t stream) {
    const float* x   = (const float*)d_in[0];
    const float* g1  = (const float*)d_in[1];
    const float* be1 = (const float*)d_in[2];
    const float* m1  = (const float*)d_in[3];
    const float* v1  = (const float*)d_in[4];
    const float* W1  = (const float*)d_in[5];
    const float* b1  = (const float*)d_in[6];
    const float* g2  = (const float*)d_in[7];
    const float* be2 = (const float*)d_in[8];
    const float* m2  = (const float*)d_in[9];
    const float* v2  = (const float*)d_in[10];
    const float* W3  = (const float*)d_in[11];
    const float* b3  = (const float*)d_in[12];
    const float* g3  = (const float*)d_in[13];
    const float* be3 = (const float*)d_in[14];
    const float* m3  = (const float*)d_in[15];
    const float* v3  = (const float*)d_in[16];
    const float* W2  = (const float*)d_in[17];
    const float* b2  = (const float*)d_in[18];
    float* out = (float*)d_out;
    float* ws  = (float*)d_ws;

    prep_kernel<<<64, 256, 0, stream>>>(g1, be1, m1, v1, W1, b1, g2, be2, m2,
                                        v2, W3, b3, g3, be3, m3, v3, W2, b2, ws);
    stage1_kernel<<<784 * 2, 512, 0, stream>>>(x, ws, ws + OFF_U);
    stage2_kernel<<<448 * 2, 256, 0, stream>>>(x, ws, ws + OFF_U, out);
}